// Round 3
// baseline (138.927 us; speedup 1.0000x reference)
//
#include <hip/hip_runtime.h>

#define NSAMP 2048
#define DIM 1024
#define NCLS 224
#define PERCLS 224
#define NSPLIT 4
#define DSL (DIM / NSPLIT)        // 256 k per block
#define CH 16                     // samples per tile
#define PAD 18                    // xs row stride (floats): even (float2 align), 2-way-free staging banks
#define TOPBLKS ((NSAMP / CH) * NSPLIT)   // 128*4 = 512
#define BOTBLKS (NCLS * NSPLIT)           // 224*4 = 896

struct Ws {
  int cls[NSAMP];
  int within[NSAMP];
  int order[NSAMP];
  int offsets[NCLS + 1];
  float top_part[NSPLIT][NSAMP][NCLS];
  float bot_part[NSPLIT][NSAMP][PERCLS];
};

// ---------------- prep: cls/within + class-grouped sample order ----------------
__global__ __launch_bounds__(256) void prep_kernel(const int* __restrict__ target,
                                                   Ws* __restrict__ ws) {
  __shared__ int cnt[NCLS];
  __shared__ int cur[NCLS];
  __shared__ int sc[256];
  int tid = threadIdx.x;
  for (int c = tid; c < NCLS; c += 256) cnt[c] = 0;
  __syncthreads();
  for (int n = tid; n < NSAMP; n += 256) {
    int t = target[n];
    int c = t / PERCLS;
    ws->cls[n] = c;
    ws->within[n] = t - c * PERCLS;
    atomicAdd(&cnt[c], 1);
  }
  __syncthreads();
  // parallel inclusive scan over 256 slots (cnt padded with 0)
  int v = (tid < NCLS) ? cnt[tid] : 0;
  sc[tid] = v;
  __syncthreads();
  for (int off = 1; off < 256; off <<= 1) {
    int a = (tid >= off) ? sc[tid - off] : 0;
    __syncthreads();
    sc[tid] += a;
    __syncthreads();
  }
  if (tid < NCLS) {
    int excl = sc[tid] - cnt[tid];
    ws->offsets[tid] = excl;
    cur[tid] = excl;
  }
  if (tid == 0) ws->offsets[NCLS] = NSAMP;
  __syncthreads();
  for (int n = tid; n < NSAMP; n += 256) {
    int c = ws->cls[n];
    int pos = atomicAdd(&cur[c], 1);
    ws->order[pos] = n;
  }
}

// ---------------- partial: register-tiled D-split partial logits --------------
// thread tile: 2 samples x 7 cols. tid = cg*8 + sg? -> sg = tid&7, cg = tid>>3.
__global__ __launch_bounds__(256) void partial_kernel(const float* __restrict__ x,
                                                      const float* __restrict__ tw,
                                                      const float* __restrict__ bw,
                                                      Ws* __restrict__ ws) {
  __shared__ float xs[DSL][PAD];   // 18 KB, transposed [k][sample]
  const int tid = threadIdx.x;
  const int bid = blockIdx.x;
  const int sg = tid & 7;          // sample group -> samples 2sg, 2sg+1
  const int cg = tid >> 3;         // 0..31 -> cols cg*7 .. cg*7+6
  const int ss = tid & 15;         // staging: sample
  const int kq0 = tid >> 4;        // staging: float4-k index base (0..15)

  if (bid < TOPBLKS) {
    // ======== top branch ========
    const int sc_ = bid >> 2;
    const int dc = bid & 3;
    const int n0 = sc_ * CH;
    const int dbase = dc * DSL;

#pragma unroll
    for (int pass = 0; pass < 4; ++pass) {
      int kq = kq0 + pass * 16;
      float4 v = *(const float4*)(x + (size_t)(n0 + ss) * DIM + dbase + kq * 4);
      xs[kq * 4 + 0][ss] = v.x;
      xs[kq * 4 + 1][ss] = v.y;
      xs[kq * 4 + 2][ss] = v.z;
      xs[kq * 4 + 3][ss] = v.w;
    }
    __syncthreads();

    float acc[2][7];
#pragma unroll
    for (int t = 0; t < 2; ++t)
#pragma unroll
      for (int j = 0; j < 7; ++j) acc[t][j] = 0.f;

    const float* Wk = tw + (size_t)dbase * NCLS + cg * 7;
#pragma unroll 4
    for (int k = 0; k < DSL; ++k) {
      float2 xv = *(const float2*)&xs[k][sg * 2];
      float w[7];
#pragma unroll
      for (int j = 0; j < 7; ++j) w[j] = Wk[j];
#pragma unroll
      for (int j = 0; j < 7; ++j) {
        acc[0][j] = fmaf(xv.x, w[j], acc[0][j]);
        acc[1][j] = fmaf(xv.y, w[j], acc[1][j]);
      }
      Wk += NCLS;
    }
#pragma unroll
    for (int t = 0; t < 2; ++t) {
      int n = n0 + sg * 2 + t;
#pragma unroll
      for (int j = 0; j < 7; ++j) ws->top_part[dc][n][cg * 7 + j] = acc[t][j];
    }
  } else {
    // ======== bottom branch ========
    const int b = bid - TOPBLKS;
    const int c = b >> 2;
    const int dc = b & 3;
    const int start = ws->offsets[c];
    const int K = ws->offsets[c + 1] - start;
    if (K == 0) return;
    const int dbase = dc * DSL;
    const float* Wbase = bw + (size_t)c * (DIM * PERCLS) + (size_t)dbase * PERCLS + cg * 7;

    for (int chunk = 0; chunk < K; chunk += CH) {
      const int S = min(CH, K - chunk);
      if (chunk) __syncthreads();

      int idx = start + chunk + ss;
      if (ss >= S) idx = start;           // clamp; value unused
      const int n_st = ws->order[idx];
#pragma unroll
      for (int pass = 0; pass < 4; ++pass) {
        int kq = kq0 + pass * 16;
        float4 v = *(const float4*)(x + (size_t)n_st * DIM + dbase + kq * 4);
        xs[kq * 4 + 0][ss] = v.x;
        xs[kq * 4 + 1][ss] = v.y;
        xs[kq * 4 + 2][ss] = v.z;
        xs[kq * 4 + 3][ss] = v.w;
      }
      __syncthreads();

      float acc[2][7];
#pragma unroll
      for (int t = 0; t < 2; ++t)
#pragma unroll
        for (int j = 0; j < 7; ++j) acc[t][j] = 0.f;

      const float* Wk = Wbase;
#pragma unroll 4
      for (int k = 0; k < DSL; ++k) {
        float2 xv = *(const float2*)&xs[k][sg * 2];
        float w[7];
#pragma unroll
        for (int j = 0; j < 7; ++j) w[j] = Wk[j];
#pragma unroll
        for (int j = 0; j < 7; ++j) {
          acc[0][j] = fmaf(xv.x, w[j], acc[0][j]);
          acc[1][j] = fmaf(xv.y, w[j], acc[1][j]);
        }
        Wk += PERCLS;
      }
#pragma unroll
      for (int t = 0; t < 2; ++t) {
        int sl = sg * 2 + t;
        if (sl < S) {
          int n = ws->order[start + chunk + sl];
#pragma unroll
          for (int j = 0; j < 7; ++j) ws->bot_part[dc][n][cg * 7 + j] = acc[t][j];
        }
      }
    }
  }
}

// ---------------- final: reduce partials + both softmaxes + product -----------
__global__ __launch_bounds__(256) void final_kernel(const float* __restrict__ tb,
                                                    const float* __restrict__ bb,
                                                    const Ws* __restrict__ ws,
                                                    float* __restrict__ out) {
  __shared__ float lt[8][NCLS];
  __shared__ float lb[8][NCLS];
  const int tid = threadIdx.x;
  const int n0 = blockIdx.x * 8;
  const int p = tid;

  if (p < NCLS) {
    float tbias = tb[p];
#pragma unroll
    for (int s = 0; s < 8; ++s) {
      int n = n0 + s;
      int c = ws->cls[n];
      float t = tbias;
      float b = bb[(size_t)c * PERCLS + p];
#pragma unroll
      for (int dc = 0; dc < NSPLIT; ++dc) t += ws->top_part[dc][n][p];
#pragma unroll
      for (int dc = 0; dc < NSPLIT; ++dc) b += ws->bot_part[dc][n][p];
      lt[s][p] = t;
      lb[s][p] = b;
    }
  }
  __syncthreads();

  const int wv = tid >> 6, lane = tid & 63;
  for (int s = wv * 2; s < wv * 2 + 2; ++s) {
    const int n = n0 + s;
    float v[4], mx = -INFINITY;
#pragma unroll
    for (int j = 0; j < 4; ++j) {
      int pp = lane + 64 * j;
      v[j] = (pp < NCLS) ? lt[s][pp] : -INFINITY;
      mx = fmaxf(mx, v[j]);
    }
#pragma unroll
    for (int m = 32; m >= 1; m >>= 1) mx = fmaxf(mx, __shfl_xor(mx, m));
    float sum = 0.f;
#pragma unroll
    for (int j = 0; j < 4; ++j) {
      int pp = lane + 64 * j;
      if (pp < NCLS) sum += expf(v[j] - mx);
    }
#pragma unroll
    for (int m = 32; m >= 1; m >>= 1) sum += __shfl_xor(sum, m);
    float pt = expf(lt[s][ws->cls[n]] - mx) / sum;

    float mb = -INFINITY;
#pragma unroll
    for (int j = 0; j < 4; ++j) {
      int pp = lane + 64 * j;
      v[j] = (pp < NCLS) ? lb[s][pp] : -INFINITY;
      mb = fmaxf(mb, v[j]);
    }
#pragma unroll
    for (int m = 32; m >= 1; m >>= 1) mb = fmaxf(mb, __shfl_xor(mb, m));
    float sb = 0.f;
#pragma unroll
    for (int j = 0; j < 4; ++j) {
      int pp = lane + 64 * j;
      if (pp < NCLS) sb += expf(v[j] - mb);
    }
#pragma unroll
    for (int m = 32; m >= 1; m >>= 1) sb += __shfl_xor(sb, m);
    float pb = expf(lb[s][ws->within[n]] - mb) / sb;

    if (lane == 0) out[n] = pt * pb;
  }
}

extern "C" void kernel_launch(void* const* d_in, const int* in_sizes, int n_in,
                              void* d_out, int out_size, void* d_ws, size_t ws_size,
                              hipStream_t stream) {
  const float* x  = (const float*)d_in[0];
  const int* tgt  = (const int*)d_in[1];
  const float* tw = (const float*)d_in[2];
  const float* tb = (const float*)d_in[3];
  const float* bw = (const float*)d_in[4];
  const float* bb = (const float*)d_in[5];
  float* out = (float*)d_out;
  Ws* ws = (Ws*)d_ws;

  prep_kernel<<<1, 256, 0, stream>>>(tgt, ws);
  partial_kernel<<<TOPBLKS + BOTBLKS, 256, 0, stream>>>(x, tw, bw, ws);
  final_kernel<<<NSAMP / 8, 256, 0, stream>>>(tb, bb, ws, out);
}

// Round 4
// 119.597 us; speedup vs baseline: 1.1616x; 1.1616x over previous
//
#include <hip/hip_runtime.h>

#define NSAMP 2048
#define DIM 1024
#define NCLS 224
#define PERCLS 224
#define CH 16
#define KSL 256                    // k per partial slice
#define NSLICE 4                   // 2 block-slices x 2 k-groups
#define TOPBLKS ((NSAMP / CH) * 2) // 256
#define BOTBLKS (NCLS * 2)         // 448

struct Ws {
  int cls[NSAMP];
  int within[NSAMP];
  int order[NSAMP];
  int offsets[NCLS + 1];
  float top_part[NSLICE][NSAMP][NCLS];
  float bot_part[NSLICE][NSAMP][PERCLS];
};

// ---------------- prep: cls/within + class-grouped sample order ----------------
__global__ __launch_bounds__(256) void prep_kernel(const int* __restrict__ target,
                                                   Ws* __restrict__ ws) {
  __shared__ int cnt[NCLS];
  __shared__ int cur[NCLS];
  __shared__ int sc[256];
  int tid = threadIdx.x;
  for (int c = tid; c < NCLS; c += 256) cnt[c] = 0;
  __syncthreads();
  for (int n = tid; n < NSAMP; n += 256) {
    int t = target[n];
    int c = t / PERCLS;
    ws->cls[n] = c;
    ws->within[n] = t - c * PERCLS;
    atomicAdd(&cnt[c], 1);
  }
  __syncthreads();
  int v = (tid < NCLS) ? cnt[tid] : 0;
  sc[tid] = v;
  __syncthreads();
  for (int off = 1; off < 256; off <<= 1) {
    int a = (tid >= off) ? sc[tid - off] : 0;
    __syncthreads();
    sc[tid] += a;
    __syncthreads();
  }
  if (tid < NCLS) {
    int excl = sc[tid] - cnt[tid];
    ws->offsets[tid] = excl;
    cur[tid] = excl;
  }
  if (tid == 0) ws->offsets[NCLS] = NSAMP;
  __syncthreads();
  for (int n = tid; n < NSAMP; n += 256) {
    int c = ws->cls[n];
    int pos = atomicAdd(&cur[c], 1);
    ws->order[pos] = n;
  }
}

// ---------------- partial: streamed-weight D-split partial logits -------------
// block = 2 k-groups x 128 threads; per k-group: 112 col-threads x 2 cols.
// x staged in LDS, read as wave-uniform broadcast b128; weights streamed
// global->VGPR as coalesced float2, each byte read exactly once per kernel.
__global__ __launch_bounds__(256) void partial_kernel(const float* __restrict__ x,
                                                      const float* __restrict__ tw,
                                                      const float* __restrict__ bw,
                                                      Ws* __restrict__ ws) {
  __shared__ float xs[2][CH][KSL];   // 32 KB
  const int tid = threadIdx.x;
  const int kg = tid >> 7;           // k-group 0/1
  const int ct = tid & 127;          // col-thread; active if < 112
  const int bid = blockIdx.x;

  const bool is_top = bid < TOPBLKS;
  int n0 = 0, c = 0, d0, start = 0, K = CH;
  if (is_top) {
    d0 = bid & 1;
    n0 = (bid >> 1) * CH;
  } else {
    int b = bid - TOPBLKS;
    d0 = b & 1;
    c = b >> 1;
    start = ws->offsets[c];
    K = ws->offsets[c + 1] - start;
    if (K == 0) return;
  }
  const int dbase = d0 * (2 * KSL) + kg * KSL;  // this thread's k-slice origin
  const int slice = d0 * 2 + kg;
  const float* Wbase = is_top ? (tw + (size_t)dbase * NCLS)
                              : (bw + (size_t)c * (DIM * PERCLS) + (size_t)dbase * PERCLS);
  const float2* W2 = (const float2*)Wbase + ct;  // col pair (2ct, 2ct+1) at k=dbase

  for (int chunk = 0; chunk < K; chunk += CH) {
    const int S = min(CH, K - chunk);
    if (chunk) __syncthreads();

    // stage x: 2048 float4, 8 per thread, coalesced within each row
#pragma unroll
    for (int pass = 0; pass < 8; ++pass) {
      int i = tid + pass * 256;
      int skg = i >> 10;
      int ss = (i >> 6) & 15;
      int q = i & 63;
      int n;
      if (is_top) {
        n = n0 + ss;
      } else {
        int idx = chunk + ss;
        n = ws->order[start + (idx < K ? idx : 0)];
      }
      ((float4*)xs)[i] =
          *(const float4*)(x + (size_t)n * DIM + d0 * (2 * KSL) + skg * KSL + q * 4);
    }
    __syncthreads();

    float2 acc[CH];
#pragma unroll
    for (int s = 0; s < CH; ++s) acc[s] = make_float2(0.f, 0.f);

    if (ct < 112) {
      const float2* Wp = W2;
      for (int k8 = 0; k8 < KSL / 8; ++k8) {
        float2 w2[8];
#pragma unroll
        for (int j = 0; j < 8; ++j) w2[j] = Wp[j * 112];
        Wp += 8 * 112;
#pragma unroll
        for (int s = 0; s < CH; ++s) {
          float xv[8];
          *(float4*)&xv[0] = *(const float4*)&xs[kg][s][k8 * 8];
          *(float4*)&xv[4] = *(const float4*)&xs[kg][s][k8 * 8 + 4];
#pragma unroll
          for (int j = 0; j < 8; ++j) {
            acc[s].x = fmaf(xv[j], w2[j].x, acc[s].x);
            acc[s].y = fmaf(xv[j], w2[j].y, acc[s].y);
          }
        }
      }

      if (is_top) {
#pragma unroll
        for (int s = 0; s < CH; ++s)
          *(float2*)&ws->top_part[slice][n0 + s][ct * 2] = acc[s];
      } else {
        for (int s = 0; s < S; ++s) {
          int n = ws->order[start + chunk + s];
          *(float2*)&ws->bot_part[slice][n][ct * 2] = acc[s];
        }
      }
    }
  }
}

// ---------------- final: reduce partials + both softmaxes + product -----------
__global__ __launch_bounds__(256) void final_kernel(const float* __restrict__ tb,
                                                    const float* __restrict__ bb,
                                                    const Ws* __restrict__ ws,
                                                    float* __restrict__ out) {
  __shared__ float lt[8][NCLS];
  __shared__ float lb[8][NCLS];
  const int tid = threadIdx.x;
  const int n0 = blockIdx.x * 8;
  const int p = tid;

  if (p < NCLS) {
    float tbias = tb[p];
#pragma unroll
    for (int s = 0; s < 8; ++s) {
      int n = n0 + s;
      int c = ws->cls[n];
      float t = tbias;
      float b = bb[(size_t)c * PERCLS + p];
#pragma unroll
      for (int dc = 0; dc < NSLICE; ++dc) t += ws->top_part[dc][n][p];
#pragma unroll
      for (int dc = 0; dc < NSLICE; ++dc) b += ws->bot_part[dc][n][p];
      lt[s][p] = t;
      lb[s][p] = b;
    }
  }
  __syncthreads();

  const int wv = tid >> 6, lane = tid & 63;
  for (int s = wv * 2; s < wv * 2 + 2; ++s) {
    const int n = n0 + s;
    float v[4], mx = -INFINITY;
#pragma unroll
    for (int j = 0; j < 4; ++j) {
      int pp = lane + 64 * j;
      v[j] = (pp < NCLS) ? lt[s][pp] : -INFINITY;
      mx = fmaxf(mx, v[j]);
    }
#pragma unroll
    for (int m = 32; m >= 1; m >>= 1) mx = fmaxf(mx, __shfl_xor(mx, m));
    float sum = 0.f;
#pragma unroll
    for (int j = 0; j < 4; ++j) {
      int pp = lane + 64 * j;
      if (pp < NCLS) sum += expf(v[j] - mx);
    }
#pragma unroll
    for (int m = 32; m >= 1; m >>= 1) sum += __shfl_xor(sum, m);
    float pt = expf(lt[s][ws->cls[n]] - mx) / sum;

    float mb = -INFINITY;
#pragma unroll
    for (int j = 0; j < 4; ++j) {
      int pp = lane + 64 * j;
      v[j] = (pp < NCLS) ? lb[s][pp] : -INFINITY;
      mb = fmaxf(mb, v[j]);
    }
#pragma unroll
    for (int m = 32; m >= 1; m >>= 1) mb = fmaxf(mb, __shfl_xor(mb, m));
    float sb = 0.f;
#pragma unroll
    for (int j = 0; j < 4; ++j) {
      int pp = lane + 64 * j;
      if (pp < NCLS) sb += expf(v[j] - mb);
    }
#pragma unroll
    for (int m = 32; m >= 1; m >>= 1) sb += __shfl_xor(sb, m);
    float pb = expf(lb[s][ws->within[n]] - mb) / sb;

    if (lane == 0) out[n] = pt * pb;
  }
}

extern "C" void kernel_launch(void* const* d_in, const int* in_sizes, int n_in,
                              void* d_out, int out_size, void* d_ws, size_t ws_size,
                              hipStream_t stream) {
  const float* x  = (const float*)d_in[0];
  const int* tgt  = (const int*)d_in[1];
  const float* tw = (const float*)d_in[2];
  const float* tb = (const float*)d_in[3];
  const float* bw = (const float*)d_in[4];
  const float* bb = (const float*)d_in[5];
  float* out = (float*)d_out;
  Ws* ws = (Ws*)d_ws;

  prep_kernel<<<1, 256, 0, stream>>>(tgt, ws);
  partial_kernel<<<TOPBLKS + BOTBLKS, 256, 0, stream>>>(x, tw, bw, ws);
  final_kernel<<<NSAMP / 8, 256, 0, stream>>>(tb, bb, ws, out);
}